// Round 1
// baseline (971.398 us; speedup 1.0000x reference)
//
#include <hip/hip_runtime.h>
#include <stdint.h>

#define T_STEPS 512
#define F_IN 30
#define HID 32
#define ROWS 16   // batch rows per block (one MFMA M-tile)

typedef __attribute__((ext_vector_type(8))) short short8;   // 8 bf16 (4 VGPRs)
typedef __attribute__((ext_vector_type(4))) float floatx4;  // 4 f32 acc

#define MFMA(a, b, c) __builtin_amdgcn_mfma_f32_16x16x32_bf16((a), (b), (c), 0, 0, 0)

__device__ __forceinline__ unsigned short f2bf(float f) {
    uint32_t u = __float_as_uint(f);
    u += 0x7fffu + ((u >> 16) & 1u);            // RTNE
    return (unsigned short)(u >> 16);
}
__device__ __forceinline__ float bf2f(unsigned short h) {
    return __uint_as_float(((uint32_t)h) << 16);
}
__device__ __forceinline__ uint32_t pack_hl(float f) {
    unsigned short hi = f2bf(f);
    unsigned short lo = f2bf(f - bf2f(hi));      // exact residual split
    return (uint32_t)hi | ((uint32_t)lo << 16);
}
__device__ __forceinline__ float sigm(float x)      { return 1.0f / (1.0f + __expf(-x)); }
__device__ __forceinline__ float tanh_fast(float x) { return 1.0f - 2.0f / (1.0f + __expf(2.0f * x)); }

__global__ __launch_bounds__(256, 1)
void lstm_fused_kernel(const float* __restrict__ x, const float* __restrict__ h0,
                       const float* __restrict__ c0, const float* __restrict__ W_ih,
                       const float* __restrict__ W_hh, const float* __restrict__ b_ih,
                       const float* __restrict__ b_hh, const float* __restrict__ W_all,
                       const float* __restrict__ b_all, const float* __restrict__ W_pos,
                       const float* __restrict__ b_pos, const float* __restrict__ W_lv,
                       const float* __restrict__ b_lv, float* __restrict__ pos_out,
                       float* __restrict__ lv_out, float* __restrict__ hT_out,
                       float* __restrict__ cT_out)
{
    const int tid  = threadIdx.x;
    const int wv   = tid >> 6;     // wave 0..3 == gate type i/f/g/o
    const int lane = tid & 63;
    const int quad = lane >> 4;
    const int l15  = lane & 15;
    const int rowbase = blockIdx.x * ROWS;

    // gate exchange buffer: stride 33 breaks pow2 bank pattern (<=2-way)
    __shared__ float gbuf[4][ROWS][33];
    // h (hi|lo bf16 packed) for next-step A-fragment; stride 36 keeps 16B align
    __shared__ __align__(16) uint32_t hbuf[ROWS][36];

    // ---- weight B-fragments: B[k=quad*8+j][n=l15], 2 n-tiles x 2 k-chunks, hi/lo split ----
    short8 wbh[2][2], wbl[2][2];
#pragma unroll
    for (int tile = 0; tile < 2; ++tile) {
        const int g = wv * 32 + tile * 16 + l15;      // gate column
#pragma unroll
        for (int kc = 0; kc < 2; ++kc) {
            short8 hh, ll;
#pragma unroll
            for (int j = 0; j < 8; ++j) {
                const int kk = quad * 8 + j;          // 0..31 within chunk
                float w;
                if (kc == 0) w = (kk < F_IN) ? W_ih[g * F_IN + kk] : 0.0f;  // x part (pad 30,31)
                else         w = W_hh[g * HID + kk];                         // h part
                unsigned short hi = f2bf(w);
                unsigned short lo = f2bf(w - bf2f(hi));
                hh[j] = (short)hi; ll[j] = (short)lo;
            }
            wbh[tile][kc] = hh; wbl[tile][kc] = ll;
        }
    }
    const float bias0 = b_ih[wv * 32 + l15]      + b_hh[wv * 32 + l15];
    const float bias1 = b_ih[wv * 32 + 16 + l15] + b_hh[wv * 32 + 16 + l15];

    // ---- update-thread state: thread owns (row um, hidden pair uj,uj+1) ----
    const int um = tid >> 4;          // 0..15
    const int uj = (tid & 15) * 2;    // 0,2,..,30
    const int urow = rowbase + um;    // global batch row
    float2 c_st = *(const float2*)&c0[(size_t)urow * HID + uj];
    float2 h_st = *(const float2*)&h0[(size_t)urow * HID + uj];

    // folded head weights: Wc = W_pos @ W_all  (pos = out@Wc^T + bc), lv direct
    float wc00 = 0.f, wc01 = 0.f, wc10 = 0.f, wc11 = 0.f, bc0, bc1;
    {
        float sb0 = 0.f, sb1 = 0.f;
#pragma unroll 4
        for (int jo = 0; jo < HID; ++jo) {
            const float wp0 = W_pos[jo], wp1 = W_pos[HID + jo];
            const float wa0 = W_all[jo * HID + uj], wa1 = W_all[jo * HID + uj + 1];
            wc00 += wp0 * wa0; wc01 += wp0 * wa1;
            wc10 += wp1 * wa0; wc11 += wp1 * wa1;
            sb0 += wp0 * b_all[jo]; sb1 += wp1 * b_all[jo];
        }
        bc0 = sb0 + b_pos[0]; bc1 = sb1 + b_pos[1];
    }
    const float wlv0 = W_lv[uj], wlv1 = W_lv[uj + 1], blv = b_lv[0];

    // initial h into hbuf
    hbuf[um][uj]     = pack_hl(h_st.x);
    hbuf[um][uj + 1] = pack_hl(h_st.y);
    __syncthreads();

    // x A-fragment: lane loads row l15, features quad*8..quad*8+7 (30,31 zero)
    const float* xlane = x + (size_t)(rowbase + l15) * T_STEPS * F_IN;
    const float* mrow  = x + (size_t)urow * T_STEPS * F_IN + (F_IN - 1); // mask feature

    float xr[8];
    {
        const float* p = xlane + quad * 8;   // t = 0
        float2 a0 = *(const float2*)(p + 0);
        float2 a1 = *(const float2*)(p + 2);
        float2 a2 = *(const float2*)(p + 4);
        float2 a3 = make_float2(0.f, 0.f);
        if (quad < 3) a3 = *(const float2*)(p + 6);
        xr[0]=a0.x; xr[1]=a0.y; xr[2]=a1.x; xr[3]=a1.y;
        xr[4]=a2.x; xr[5]=a2.y; xr[6]=a3.x; xr[7]=a3.y;
    }
    short8 xah, xal;
#pragma unroll
    for (int j = 0; j < 8; ++j) {
        unsigned short hi = f2bf(xr[j]);
        unsigned short lo = f2bf(xr[j] - bf2f(hi));
        xah[j] = (short)hi; xal[j] = (short)lo;
    }

    for (int t = 0; t < T_STEPS; ++t) {
        floatx4 acc0 = {bias0, bias0, bias0, bias0};
        floatx4 acc1 = {bias1, bias1, bias1, bias1};

        // x-chunk MFMAs (independent of recurrence)
        acc0 = MFMA(xah, wbh[0][0], acc0);
        acc1 = MFMA(xah, wbh[1][0], acc1);
        acc0 = MFMA(xal, wbh[0][0], acc0);
        acc1 = MFMA(xal, wbh[1][0], acc1);
        acc0 = MFMA(xah, wbl[0][0], acc0);
        acc1 = MFMA(xah, wbl[1][0], acc1);

        // h A-fragment from LDS (written end of previous step)
        uint32_t hw[8];
        *(uint4*)&hw[0] = *(const uint4*)&hbuf[l15][quad * 8];
        *(uint4*)&hw[4] = *(const uint4*)&hbuf[l15][quad * 8 + 4];
        short8 hah, hal;
#pragma unroll
        for (int j = 0; j < 8; ++j) {
            hah[j] = (short)(hw[j] & 0xffffu);
            hal[j] = (short)(hw[j] >> 16);
        }

        // prefetch next x tile (clamped; quad3 tail predicated to avoid OOB)
        float xnr[8];
        {
            const int tn = (t + 1 < T_STEPS) ? t + 1 : t;
            const float* p = xlane + tn * F_IN + quad * 8;
            float2 a0 = *(const float2*)(p + 0);
            float2 a1 = *(const float2*)(p + 2);
            float2 a2 = *(const float2*)(p + 4);
            float2 a3 = make_float2(0.f, 0.f);
            if (quad < 3) a3 = *(const float2*)(p + 6);
            xnr[0]=a0.x; xnr[1]=a0.y; xnr[2]=a1.x; xnr[3]=a1.y;
            xnr[4]=a2.x; xnr[5]=a2.y; xnr[6]=a3.x; xnr[7]=a3.y;
        }

        // h-chunk MFMAs
        acc0 = MFMA(hah, wbh[0][1], acc0);
        acc1 = MFMA(hah, wbh[1][1], acc1);
        acc0 = MFMA(hal, wbh[0][1], acc0);
        acc1 = MFMA(hal, wbh[1][1], acc1);
        acc0 = MFMA(hah, wbl[0][1], acc0);
        acc1 = MFMA(hah, wbl[1][1], acc1);

        // wave-uniform activation, write to gate buffer
#pragma unroll
        for (int r = 0; r < 4; ++r) {
            float a0 = acc0[r], a1 = acc1[r];
            if (wv == 2) { a0 = tanh_fast(a0); a1 = tanh_fast(a1); }
            else         { a0 = sigm(a0);      a1 = sigm(a1);      }
            const int m = quad * 4 + r;       // C-layout row
            gbuf[wv][m][l15]      = a0;
            gbuf[wv][m][l15 + 16] = a1;
        }
        __syncthreads();

        // ---- state update (thread = (um, uj..uj+1)) ----
        const float gi0 = gbuf[0][um][uj], gi1 = gbuf[0][um][uj + 1];
        const float gf0 = gbuf[1][um][uj], gf1 = gbuf[1][um][uj + 1];
        const float gg0 = gbuf[2][um][uj], gg1 = gbuf[2][um][uj + 1];
        const float go0 = gbuf[3][um][uj], go1 = gbuf[3][um][uj + 1];

        const float mv = mrow[t * F_IN];
        const bool on = (mv == 1.0f);

        const float cn0 = gf0 * c_st.x + gi0 * gg0;
        const float cn1 = gf1 * c_st.y + gi1 * gg1;
        const float hn0 = go0 * tanh_fast(cn0);
        const float hn1 = go1 * tanh_fast(cn1);
        if (on) { c_st.x = cn0; c_st.y = cn1; h_st.x = hn0; h_st.y = hn1; }
        const float out0 = on ? hn0 : 0.0f;
        const float out1 = on ? hn1 : 0.0f;

        hbuf[um][uj]     = pack_hl(h_st.x);
        hbuf[um][uj + 1] = pack_hl(h_st.y);

        // fused heads: reduce across the 16 threads sharing row um
        float p0 = wc00 * out0 + wc01 * out1;
        float p1 = wc10 * out0 + wc11 * out1;
        float pl = wlv0 * out0 + wlv1 * out1;
#pragma unroll
        for (int d = 1; d < 16; d <<= 1) {
            p0 += __shfl_xor(p0, d);
            p1 += __shfl_xor(p1, d);
            pl += __shfl_xor(pl, d);
        }
        if ((tid & 15) == 0) {
            const size_t o = (size_t)urow * T_STEPS + t;
            *(float2*)&pos_out[o * 2] = make_float2(p0 + bc0, p1 + bc1);
            lv_out[o] = sigm(pl + blv);
        }

        // finish next-step x fragment conversion
#pragma unroll
        for (int j = 0; j < 8; ++j) {
            unsigned short hi = f2bf(xnr[j]);
            unsigned short lo = f2bf(xnr[j] - bf2f(hi));
            xah[j] = (short)hi; xal[j] = (short)lo;
        }
        __syncthreads();
    }

    *(float2*)&hT_out[(size_t)urow * HID + uj] = h_st;
    *(float2*)&cT_out[(size_t)urow * HID + uj] = c_st;
}

extern "C" void kernel_launch(void* const* d_in, const int* in_sizes, int n_in,
                              void* d_out, int out_size, void* d_ws, size_t ws_size,
                              hipStream_t stream) {
    const float* x     = (const float*)d_in[0];
    const float* h0    = (const float*)d_in[1];
    const float* c0    = (const float*)d_in[2];
    const float* W_ih  = (const float*)d_in[3];
    const float* W_hh  = (const float*)d_in[4];
    const float* b_ih  = (const float*)d_in[5];
    const float* b_hh  = (const float*)d_in[6];
    const float* W_all = (const float*)d_in[7];
    const float* b_all = (const float*)d_in[8];
    const float* W_pos = (const float*)d_in[9];
    const float* b_pos = (const float*)d_in[10];
    const float* W_lv  = (const float*)d_in[11];
    const float* b_lv  = (const float*)d_in[12];

    const int B = in_sizes[1] / HID;         // h0 is [1,B,H] -> 4096
    float* out     = (float*)d_out;
    float* pos_out = out;                                    // [B,T,2]
    float* lv_out  = pos_out + (size_t)B * T_STEPS * 2;      // [B,T,1]
    float* hT_out  = lv_out  + (size_t)B * T_STEPS;          // [1,B,H]
    float* cT_out  = hT_out  + (size_t)B * HID;              // [1,B,H]

    dim3 grid(B / ROWS), block(256);
    hipLaunchKernelGGL(lstm_fused_kernel, grid, block, 0, stream,
                       x, h0, c0, W_ih, W_hh, b_ih, b_hh, W_all, b_all,
                       W_pos, b_pos, W_lv, b_lv, pos_out, lv_out, hT_out, cT_out);
}

// Round 2
// 955.097 us; speedup vs baseline: 1.0171x; 1.0171x over previous
//
#include <hip/hip_runtime.h>
#include <stdint.h>

#define T_STEPS 512
#define F_IN 30
#define HID 32
#define ROWS 16   // batch rows per block (one MFMA M-tile)

typedef __attribute__((ext_vector_type(8))) short short8;   // 8 bf16 (4 VGPRs)
typedef __attribute__((ext_vector_type(4))) float floatx4;  // 4 f32 acc

#define MFMA(a, b, c) __builtin_amdgcn_mfma_f32_16x16x32_bf16((a), (b), (c), 0, 0, 0)

// Raw barrier: drain LDS only (lgkmcnt), let global loads/stores ride across.
// Safe because ALL cross-thread data flows through LDS; global loads are
// thread-private prefetches, global stores are never read back.
#define BAR() asm volatile("s_waitcnt lgkmcnt(0)\n\ts_barrier" ::: "memory")

__device__ __forceinline__ unsigned short f2bf(float f) {
    uint32_t u = __float_as_uint(f);
    u += 0x7fffu + ((u >> 16) & 1u);            // RTNE
    return (unsigned short)(u >> 16);
}
__device__ __forceinline__ float bf2f(unsigned short h) {
    return __uint_as_float(((uint32_t)h) << 16);
}
__device__ __forceinline__ uint32_t pack_hl(float f) {
    unsigned short hi = f2bf(f);
    unsigned short lo = f2bf(f - bf2f(hi));      // exact residual split
    return (uint32_t)hi | ((uint32_t)lo << 16);
}
__device__ __forceinline__ float sigm(float x)      { return 1.0f / (1.0f + __expf(-x)); }
__device__ __forceinline__ float tanh_fast(float x) { return 1.0f - 2.0f / (1.0f + __expf(2.0f * x)); }

__device__ __forceinline__ void loadx8(float (&d)[8], const float* p, bool tail) {
    float2 a0 = *(const float2*)(p + 0);
    float2 a1 = *(const float2*)(p + 2);
    float2 a2 = *(const float2*)(p + 4);
    float2 a3 = make_float2(0.f, 0.f);
    if (!tail) a3 = *(const float2*)(p + 6);     // quad3 covers features 24..29 + zero pad
    d[0]=a0.x; d[1]=a0.y; d[2]=a1.x; d[3]=a1.y;
    d[4]=a2.x; d[5]=a2.y; d[6]=a3.x; d[7]=a3.y;
}

__global__ __launch_bounds__(512, 1)
void lstm_fused_kernel(const float* __restrict__ x, const float* __restrict__ h0,
                       const float* __restrict__ c0, const float* __restrict__ W_ih,
                       const float* __restrict__ W_hh, const float* __restrict__ b_ih,
                       const float* __restrict__ b_hh, const float* __restrict__ W_all,
                       const float* __restrict__ b_all, const float* __restrict__ W_pos,
                       const float* __restrict__ b_pos, const float* __restrict__ W_lv,
                       const float* __restrict__ b_lv, float* __restrict__ pos_out,
                       float* __restrict__ lv_out, float* __restrict__ hT_out,
                       float* __restrict__ cT_out)
{
    const int tid  = threadIdx.x;
    const int wv   = tid >> 6;        // wave 0..7 == n-tile; gate type = wv>>1
    const int lane = tid & 63;
    const int quad = lane >> 4;
    const int l15  = lane & 15;
    const int rowbase = blockIdx.x * ROWS;

    __shared__ float gbuf[ROWS][132];                       // [row][gate 0..127], +4 pad
    __shared__ __align__(16) uint32_t hbuf[ROWS][36];       // packed hi|lo bf16 h

    // ---- B-fragments for this wave's n-tile (gate column gcol) ----
    const int gcol = wv * 16 + l15;
    short8 wxh, wxl, whh, whl;
#pragma unroll
    for (int j = 0; j < 8; ++j) {
        const int k = quad * 8 + j;
        float wx = (k < F_IN) ? W_ih[gcol * F_IN + k] : 0.0f;
        unsigned short hx = f2bf(wx);
        wxh[j] = (short)hx; wxl[j] = (short)f2bf(wx - bf2f(hx));
        float wh = W_hh[gcol * HID + k];
        unsigned short hh = f2bf(wh);
        whh[j] = (short)hh; whl[j] = (short)f2bf(wh - bf2f(hh));
    }
    const float bias = b_ih[gcol] + b_hh[gcol];
    const bool  is_g = ((wv >> 1) == 2);

    // ---- update role: thread = (row um, hidden unit uj) ----
    const int um = tid >> 5;          // 0..15
    const int uj = tid & 31;          // 0..31
    const int urow = rowbase + um;
    float c_st = c0[(size_t)urow * HID + uj];
    float h_st = h0[(size_t)urow * HID + uj];

    // folded head weights: Wc[g][uj] = sum_o W_pos[g][o] * W_all[o][uj]
    float wc0 = 0.f, wc1 = 0.f, sb0 = 0.f, sb1 = 0.f;
#pragma unroll 8
    for (int jo = 0; jo < HID; ++jo) {
        const float wa = W_all[jo * HID + uj];
        wc0 += W_pos[jo] * wa;  wc1 += W_pos[HID + jo] * wa;
        sb0 += W_pos[jo] * b_all[jo];  sb1 += W_pos[HID + jo] * b_all[jo];
    }
    const float bc0 = sb0 + b_pos[0], bc1 = sb1 + b_pos[1];
    const float wlv = W_lv[uj], blv = b_lv[0];

    hbuf[um][uj] = pack_hl(h_st);

    // x A-fragment pointers: lane (l15,quad) reads row rowbase+l15, feat quad*8..+7
    const float* xlane = x + (size_t)(rowbase + l15) * T_STEPS * F_IN + quad * 8;
    const float* mptr  = x + (size_t)urow * T_STEPS * F_IN + (F_IN - 1);
    const bool tail = (quad == 3);

    // depth-4 register prefetch ring
    float xr0[8], xr1[8], xr2[8], xr3[8];
    float mr0, mr1, mr2, mr3;
    loadx8(xr0, xlane + 0 * F_IN, tail);  mr0 = mptr[0 * F_IN];
    loadx8(xr1, xlane + 1 * F_IN, tail);  mr1 = mptr[1 * F_IN];
    loadx8(xr2, xlane + 2 * F_IN, tail);  mr2 = mptr[2 * F_IN];
    loadx8(xr3, xlane + 3 * F_IN, tail);  mr3 = mptr[3 * F_IN];

    BAR();

    auto step = [&](int t, float (&xr)[8], float& mr) {
        // snapshot mask before the ring slot is overwritten
        const float mcur = mr;
        // convert current x (prefetched 4 steps ago; vmcnt long satisfied)
        short8 xah;
#pragma unroll
        for (int j = 0; j < 8; ++j) xah[j] = (short)f2bf(xr[j]);
        // issue h fragment read early
        uint32_t hw[8];
        *(uint4*)&hw[0] = *(const uint4*)&hbuf[l15][quad * 8];
        *(uint4*)&hw[4] = *(const uint4*)&hbuf[l15][quad * 8 + 4];
        // prefetch t+4 into this ring slot (rides across raw barriers)
        {
            const int tp = (t + 4 < T_STEPS) ? t + 4 : (T_STEPS - 1);
            loadx8(xr, xlane + tp * F_IN, tail);
            mr = mptr[tp * F_IN];
        }
        // x MFMAs (independent of recurrence, overlap h LDS latency)
        floatx4 acc = {bias, bias, bias, bias};
        acc = MFMA(xah, wxh, acc);
        acc = MFMA(xah, wxl, acc);
        // h MFMAs (hi/lo 3-product, ~fp32 grade)
        short8 hah, hal;
#pragma unroll
        for (int j = 0; j < 8; ++j) {
            hah[j] = (short)(hw[j] & 0xffffu);
            hal[j] = (short)(hw[j] >> 16);
        }
        acc = MFMA(hah, whh, acc);
        acc = MFMA(hal, whh, acc);
        acc = MFMA(hah, whl, acc);
        // wave-uniform activation, scatter to gate buffer (C-layout row = quad*4+r)
#pragma unroll
        for (int r = 0; r < 4; ++r) {
            float a = acc[r];
            a = is_g ? tanh_fast(a) : sigm(a);
            gbuf[quad * 4 + r][gcol] = a;
        }
        BAR();
        // ---- state update: thread = (um, uj) ----
        const float gi = gbuf[um][uj];
        const float gf = gbuf[um][32 + uj];
        const float gg = gbuf[um][64 + uj];
        const float go = gbuf[um][96 + uj];
        const float cn = gf * c_st + gi * gg;
        const float hn = go * tanh_fast(cn);
        const bool on = (mcur == 1.0f);
        if (on) { c_st = cn; h_st = hn; }
        const float out = on ? hn : 0.0f;
        hbuf[um][uj] = pack_hl(h_st);
        // fused heads: reduce across the 32 threads sharing row um (off LDS path)
        float p0 = wc0 * out, p1 = wc1 * out, pl = wlv * out;
#pragma unroll
        for (int d = 1; d < 32; d <<= 1) {
            p0 += __shfl_xor(p0, d);
            p1 += __shfl_xor(p1, d);
            pl += __shfl_xor(pl, d);
        }
        if (uj == 0) {
            const size_t o = (size_t)urow * T_STEPS + t;
            *(float2*)&pos_out[o * 2] = make_float2(p0 + bc0, p1 + bc1);
            lv_out[o] = sigm(pl + blv);
        }
        BAR();
    };

    for (int t = 0; t < T_STEPS; t += 4) {
        step(t + 0, xr0, mr0);
        step(t + 1, xr1, mr1);
        step(t + 2, xr2, mr2);
        step(t + 3, xr3, mr3);
    }

    hT_out[(size_t)urow * HID + uj] = h_st;
    cT_out[(size_t)urow * HID + uj] = c_st;
}

extern "C" void kernel_launch(void* const* d_in, const int* in_sizes, int n_in,
                              void* d_out, int out_size, void* d_ws, size_t ws_size,
                              hipStream_t stream) {
    const float* x     = (const float*)d_in[0];
    const float* h0    = (const float*)d_in[1];
    const float* c0    = (const float*)d_in[2];
    const float* W_ih  = (const float*)d_in[3];
    const float* W_hh  = (const float*)d_in[4];
    const float* b_ih  = (const float*)d_in[5];
    const float* b_hh  = (const float*)d_in[6];
    const float* W_all = (const float*)d_in[7];
    const float* b_all = (const float*)d_in[8];
    const float* W_pos = (const float*)d_in[9];
    const float* b_pos = (const float*)d_in[10];
    const float* W_lv  = (const float*)d_in[11];
    const float* b_lv  = (const float*)d_in[12];

    const int B = in_sizes[1] / HID;         // h0 is [1,B,H] -> 4096
    float* out     = (float*)d_out;
    float* pos_out = out;                                    // [B,T,2]
    float* lv_out  = pos_out + (size_t)B * T_STEPS * 2;      // [B,T,1]
    float* hT_out  = lv_out  + (size_t)B * T_STEPS;          // [1,B,H]
    float* cT_out  = hT_out  + (size_t)B * HID;              // [1,B,H]

    dim3 grid(B / ROWS), block(512);
    hipLaunchKernelGGL(lstm_fused_kernel, grid, block, 0, stream,
                       x, h0, c0, W_ih, W_hh, b_ih, b_hh, W_all, b_all,
                       W_pos, b_pos, W_lv, b_lv, pos_out, lv_out, hT_out, cT_out);
}